// Round 1
// baseline (261.533 us; speedup 1.0000x reference)
//
#include <hip/hip_runtime.h>
#include <stdint.h>

// Problem constants (fixed by the reference)
#define B_IMG        64
#define M_GT         100
#define N_PROP       4000
#define K_TOT        4100          // N + M (proposal_append_gt)
#define SORT_N       8192          // next pow2 >= K_TOT
#define NTH          1024
#define NUM_CLASSES_ 80
#define BATCH_PER    512
#define NUM_FG_TGT   128
#define OUT_STRIDE   (B_IMG * BATCH_PER)   // 32768 elements per output tensor

// IoU with contraction disabled so float32 results match the numpy reference
// bit-for-bit (an FMA-induced 1-ulp drift at the 0.5 threshold would flip
// fg/bg and scramble integer outputs).
__device__ __forceinline__ float iou_fn(float ax1, float ay1, float ax2, float ay2,
                                        float area_a,
                                        float bx1, float by1, float bx2, float by2,
                                        float area_b) {
#pragma clang fp contract(off)
    float ltx = fmaxf(ax1, bx1), lty = fmaxf(ay1, by1);
    float rbx = fminf(ax2, bx2), rby = fminf(ay2, by2);
    float wx = fmaxf(rbx - ltx, 0.0f);
    float wy = fmaxf(rby - lty, 0.0f);
    float inter = wx * wy;
    float uni = area_a + area_b - inter;
    return inter > 0.0f ? inter / uni : 0.0f;
}

__global__ __launch_bounds__(NTH) void roiheads_kernel(
        const float* __restrict__ gt_boxes,    // [B, M, 4]
        const float* __restrict__ prop_boxes,  // [B, N, 4]
        const int*   __restrict__ gt_classes,  // [B, M]
        const float* __restrict__ rand_pri,    // [B, K]
        float* __restrict__ out)               // 5 tensors of [B, 512], flat
{
    __shared__ uint64_t s_keys[SORT_N];     // 64 KiB — inverted sort keys
    __shared__ float    s_mvals[K_TOT];     // matched_vals
    __shared__ int      s_midx[K_TOT];      // matched_idxs
    __shared__ float    s_gtb[M_GT * 4];    // gt boxes (this image)
    __shared__ float    s_gta[M_GT];        // gt areas
    __shared__ int      s_gtc[M_GT];        // gt classes
    __shared__ int      s_fgcnt;

    const int b   = blockIdx.x;
    const int tid = threadIdx.x;

    // ---- stage gt data ----
    for (int i = tid; i < M_GT * 4; i += NTH)
        s_gtb[i] = gt_boxes[(size_t)b * M_GT * 4 + i];
    for (int i = tid; i < M_GT; i += NTH)
        s_gtc[i] = gt_classes[(size_t)b * M_GT + i];
    if (tid == 0) s_fgcnt = 0;
    __syncthreads();
    for (int m = tid; m < M_GT; m += NTH) {
#pragma clang fp contract(off)
        s_gta[m] = (s_gtb[m * 4 + 2] - s_gtb[m * 4 + 0]) *
                   (s_gtb[m * 4 + 3] - s_gtb[m * 4 + 1]);
    }
    __syncthreads();

    // ---- phase 1: per-box max/argmax IoU over gt, build sort keys ----
    int local_fg = 0;
    for (int k = tid; k < K_TOT; k += NTH) {
        float bx1, by1, bx2, by2;
        if (k < N_PROP) {
            const float* p = prop_boxes + ((size_t)b * N_PROP + k) * 4;
            bx1 = p[0]; by1 = p[1]; bx2 = p[2]; by2 = p[3];
        } else {
            const float* p = s_gtb + (k - N_PROP) * 4;
            bx1 = p[0]; by1 = p[1]; bx2 = p[2]; by2 = p[3];
        }
        float area_b;
        {
#pragma clang fp contract(off)
            area_b = (bx2 - bx1) * (by2 - by1);
        }
        float best = -1.0f; int bidx = 0;
        for (int m = 0; m < M_GT; ++m) {
            float q = iou_fn(s_gtb[m*4+0], s_gtb[m*4+1], s_gtb[m*4+2], s_gtb[m*4+3],
                             s_gta[m], bx1, by1, bx2, by2, area_b);
            if (q > best) { best = q; bidx = m; }   // strict > => first max (argmax semantics)
        }
        s_mvals[k] = best;
        s_midx[k]  = bidx;
        bool fg = best >= 0.5f;
        local_fg += fg ? 1 : 0;
        // key: fg(62) | real(61) | pri_bits(42..13) | idx(12..0). pri in [0,1) =>
        // bits < 2^30; positive-float bits sort like values. Descending sort on
        // key == reversed stable ascending argsort (higher idx first on ties).
        uint32_t pb = __float_as_uint(rand_pri[(size_t)b * K_TOT + k]);
        uint64_t key = (fg ? (1ull << 62) : 0ull) | (1ull << 61)
                     | ((uint64_t)pb << 13) | (uint64_t)k;
        s_keys[k] = ~key;   // sort ascending on ~key == descending on key
    }
    for (int i = K_TOT + tid; i < SORT_N; i += NTH)
        s_keys[i] = ~0ull;  // pads: max under ascending-inverted => end
    if (local_fg) atomicAdd(&s_fgcnt, local_fg);
    __syncthreads();

    // ---- phase 2: bitonic sort (ascending on inverted keys) ----
    for (int kk = 2; kk <= SORT_N; kk <<= 1) {
        for (int j = kk >> 1; j > 0; j >>= 1) {
            for (int i = tid; i < SORT_N; i += NTH) {
                int ixj = i ^ j;
                if (ixj > i) {
                    uint64_t a = s_keys[i];
                    uint64_t c = s_keys[ixj];
                    bool up = ((i & kk) == 0);
                    if ((a > c) == up) { s_keys[i] = c; s_keys[ixj] = a; }
                }
            }
            __syncthreads();
        }
    }

    // ---- phase 3: emit 512 samples ----
    int fg_count = s_fgcnt;
    if (tid < BATCH_PER) {
        int p = tid;
        int num_fg = min(NUM_FG_TGT, fg_count);
        int bg_count = K_TOT - fg_count;
        int num_bg = min(BATCH_PER - num_fg, bg_count);
        bool valid = p < num_fg + num_bg;
        float o_iou = 0.0f, o_idx = -1.0f, o_cls = -1.0f, o_gt = -1.0f;
        if (valid) {
            int pos = (p < num_fg) ? p : (fg_count + (p - num_fg));
            uint64_t orig = ~s_keys[pos];
            int idx = (int)(orig & 0x1FFFull);
            int fgf = (int)((orig >> 62) & 1ull);
            int mi  = s_midx[idx];
            o_iou = s_mvals[idx];
            o_idx = (float)idx;
            o_gt  = (float)mi;
            o_cls = (float)(fgf ? s_gtc[mi] : NUM_CLASSES_);
        }
        size_t base = (size_t)b * BATCH_PER + p;
        out[0 * OUT_STRIDE + base] = o_iou;
        out[1 * OUT_STRIDE + base] = o_idx;
        out[2 * OUT_STRIDE + base] = o_cls;
        out[3 * OUT_STRIDE + base] = o_gt;
        out[4 * OUT_STRIDE + base] = valid ? 1.0f : 0.0f;
    }
}

extern "C" void kernel_launch(void* const* d_in, const int* in_sizes, int n_in,
                              void* d_out, int out_size, void* d_ws, size_t ws_size,
                              hipStream_t stream) {
    const float* gt_boxes   = (const float*)d_in[0];  // [64,100,4]
    const float* prop_boxes = (const float*)d_in[1];  // [64,4000,4]
    const int*   gt_classes = (const int*)  d_in[2];  // [64,100]
    const float* rand_pri   = (const float*)d_in[3];  // [64,4100]
    float* out = (float*)d_out;                       // 5 x [64,512] float32, concat

    roiheads_kernel<<<B_IMG, NTH, 0, stream>>>(gt_boxes, prop_boxes, gt_classes,
                                               rand_pri, out);
}

// Round 4
// 162.754 us; speedup vs baseline: 1.6069x; 1.6069x over previous
//
#include <hip/hip_runtime.h>
#include <stdint.h>

// Problem constants (fixed by the reference)
#define B_IMG        64
#define M_GT         100
#define N_PROP       4000
#define K_TOT        4100          // N + M (proposal_append_gt)
#define NUM_CLASSES_ 80
#define BATCH_PER    512
#define NUM_FG_TGT   128
#define OUT_STRIDE   (B_IMG * BATCH_PER)   // 32768 elements per output tensor

#define NTH          1024                  // threads per block (one block per image)
#define HALF_CAP     1024                  // candidate capacity per group (fg | bg)

// Key packing (uint64 compare gives exact (fg, pri, idx) descending order;
// midx rides in the low bits — idx is unique so it never affects ordering):
//   bit 50      : fg flag
//   bits 49..20 : float bits of priority (pri in [0,1) => bits < 2^30;
//                 positive-float bits are order-isomorphic to values)
//   bits 19..7  : element index (0..4099 < 8192)  — reproduces the reversed-
//                 stable-argsort tiebreak (higher idx first on equal pri)
//   bits  6..0  : matched gt index (0..99 < 128)

// IoU with contraction disabled so float32 results match the numpy reference
// bit-for-bit (an FMA-induced 1-ulp drift at the 0.5 threshold would flip
// fg/bg and scramble integer outputs).
__device__ __forceinline__ float iou_fn(float ax1, float ay1, float ax2, float ay2,
                                        float area_a,
                                        float bx1, float by1, float bx2, float by2,
                                        float area_b) {
#pragma clang fp contract(off)
    float ltx = fmaxf(ax1, bx1), lty = fmaxf(ay1, by1);
    float rbx = fminf(ax2, bx2), rby = fminf(ay2, by2);
    float wx = fmaxf(rbx - ltx, 0.0f);
    float wy = fmaxf(rby - lty, 0.0f);
    float inter = wx * wy;
    float uni = area_a + area_b - inter;
    return inter > 0.0f ? inter / uni : 0.0f;
}

// One block per image; no workspace, no inter-kernel state (graph-replay safe).
__global__ __launch_bounds__(NTH) void roiheads_kernel(
        const float* __restrict__ gt_boxes,    // [B, M, 4]
        const float* __restrict__ prop_boxes,  // [B, N, 4]
        const int*   __restrict__ gt_classes,  // [B, M]
        const float* __restrict__ rand_pri,    // [B, K]
        float*       __restrict__ out)         // 5 x [B, 512] flat
{
    __shared__ uint64_t s_keys[K_TOT];         // 32.8 KB
    __shared__ uint64_t s_cand[2 * HALF_CAP];  // 16 KB: fg half | bg half
    __shared__ int      s_hist[2][256];        // fg / bg histograms -> suffix sums
    __shared__ float    s_gtb[M_GT * 4];
    __shared__ float    s_gta[M_GT];
    __shared__ int      s_gtc[M_GT];
    __shared__ float    s_out[5][BATCH_PER];   // 10 KB staging
    __shared__ int      s_T[2], s_needed[2], s_cnt[2];

    const int b   = blockIdx.x;
    const int tid = threadIdx.x;

    // ---- phase 0: stage gt data, zero counters ----
    for (int i = tid; i < 512; i += NTH) s_hist[i >> 8][i & 255] = 0;
    if (tid < 2) s_cnt[tid] = 0;
    for (int i = tid; i < M_GT * 4; i += NTH)
        s_gtb[i] = gt_boxes[(size_t)b * M_GT * 4 + i];
    for (int i = tid; i < M_GT; i += NTH)
        s_gtc[i] = gt_classes[(size_t)b * M_GT + i];
    __syncthreads();
    for (int m = tid; m < M_GT; m += NTH) {
#pragma clang fp contract(off)
        s_gta[m] = (s_gtb[m * 4 + 2] - s_gtb[m * 4 + 0]) *
                   (s_gtb[m * 4 + 3] - s_gtb[m * 4 + 1]);
    }
    __syncthreads();

    // ---- phase 1: per-element IoU argmax over gt, key build, histogram ----
    for (int k = tid; k < K_TOT; k += NTH) {
        float bx1, by1, bx2, by2;
        if (k < N_PROP) {
            const float4 p = *(const float4*)(prop_boxes + ((size_t)b * N_PROP + k) * 4);
            bx1 = p.x; by1 = p.y; bx2 = p.z; by2 = p.w;
        } else {
            const float* p = s_gtb + (k - N_PROP) * 4;
            bx1 = p[0]; by1 = p[1]; bx2 = p[2]; by2 = p[3];
        }
        float area_b;
        {
#pragma clang fp contract(off)
            area_b = (bx2 - bx1) * (by2 - by1);
        }
        float best = -1.0f; int bidx = 0;
        for (int m = 0; m < M_GT; ++m) {
            float q = iou_fn(s_gtb[m*4+0], s_gtb[m*4+1], s_gtb[m*4+2], s_gtb[m*4+3],
                             s_gta[m], bx1, by1, bx2, by2, area_b);
            if (q > best) { best = q; bidx = m; }   // strict > => first-occurrence argmax
        }
        const bool fg = best >= 0.5f;
        const float pri = rand_pri[(size_t)b * K_TOT + k];
        const uint32_t pb = __float_as_uint(pri);
        s_keys[k] = (fg ? (1ull << 50) : 0ull)
                  | ((uint64_t)pb << 20)
                  | ((uint64_t)k  << 7)
                  | (uint64_t)bidx;
        int g = fg ? 0 : 1;
        int bucket = min(255, (int)(pri * 256.0f));   // monotone in pri
        atomicAdd(&s_hist[g][bucket], 1);
    }
    __syncthreads();

    // ---- phase 2: Hillis-Steele suffix scan over each 256-bucket histogram ----
    for (int d = 1; d < 256; d <<= 1) {
        int v = 0, g = tid >> 8, t = tid & 255;
        bool act = (tid < 512) && (t + d < 256);
        if (act) v = s_hist[g][t + d];
        __syncthreads();
        if (act) s_hist[g][t] += v;
        __syncthreads();
    }

    if (tid == 0) {
        int fg_total = s_hist[0][0];
        int bg_total = s_hist[1][0];
        int nfg = min(NUM_FG_TGT, fg_total);
        int nbg = min(BATCH_PER - nfg, bg_total);
        s_needed[0] = nfg; s_needed[1] = nbg;
    }
    __syncthreads();

    // ---- phase 3: bucket threshold (max t with S[t] >= need; unique crossing
    // since S is non-increasing; t=255 handles need<=S[255] incl. need==0) ----
    if (tid < 512) {
        int g = tid >> 8, t = tid & 255;
        int need = s_needed[g];
        int St  = s_hist[g][t];
        int St1 = (t == 255) ? -1 : s_hist[g][t + 1];
        if (St >= need && St1 < need) s_T[g] = t;
    }
    // prefill output staging with the invalid pattern
    if (tid < BATCH_PER) {
        s_out[0][tid] = 0.0f; s_out[1][tid] = -1.0f;
        s_out[2][tid] = -1.0f; s_out[3][tid] = -1.0f;
    }
    __syncthreads();

    const int nfg = s_needed[0], nbg = s_needed[1];
    if (tid < BATCH_PER)
        s_out[4][tid] = (tid < nfg + nbg) ? 1.0f : 0.0f;

    // ---- phase 4: compaction into disjoint halves (fg -> [0,HALF_CAP),
    // bg -> [HALF_CAP, 2*HALF_CAP)) — no coupling to histogram counts ----
    for (int k = tid; k < K_TOT; k += NTH) {
        uint64_t key = s_keys[k];
        int g = ((key >> 50) & 1ull) ? 0 : 1;
        uint32_t pbits = (uint32_t)((key >> 20) & 0x3FFFFFFFull);
        int bucket = min(255, (int)(__uint_as_float(pbits) * 256.0f));
        if (bucket >= s_T[g]) {
            int pos = atomicAdd(&s_cnt[g], 1);
            if (pos < HALF_CAP) s_cand[g * HALF_CAP + pos] = key;
        }
    }
    __syncthreads();

    // ---- phase 5: rank within each half (keys unique -> ranks unique -> each
    // slot written exactly once, independent of atomic ordering) and emit ----
    const int fgc = min(s_cnt[0], HALF_CAP);
    const int bgc = min(s_cnt[1], HALF_CAP);
    for (int c = tid; c < fgc + bgc; c += NTH) {
        const bool isfg = (c < fgc);
        const int  base = isfg ? 0 : HALF_CAP;
        const int  cnt  = isfg ? fgc : bgc;
        const int  ci   = isfg ? c : (c - fgc);
        const uint64_t kc = s_cand[base + ci];
        int r = 0;
        for (int j = 0; j < cnt; ++j)            // broadcast LDS reads
            r += (s_cand[base + j] > kc) ? 1 : 0;
        int slot = -1;
        if (isfg) { if (r < nfg) slot = r; }
        else      { if (r < nbg) slot = nfg + r; }
        if (slot >= 0) {
            int idx = (int)((kc >> 7) & 0x1FFFull);
            int mi  = (int)(kc & 0x7Full);
            float bx1, by1, bx2, by2;
            if (idx < N_PROP) {
                const float4 p = *(const float4*)(prop_boxes + ((size_t)b * N_PROP + idx) * 4);
                bx1 = p.x; by1 = p.y; bx2 = p.z; by2 = p.w;
            } else {
                const float* p = s_gtb + (idx - N_PROP) * 4;
                bx1 = p[0]; by1 = p[1]; bx2 = p[2]; by2 = p[3];
            }
            float area_b;
            {
#pragma clang fp contract(off)
                area_b = (bx2 - bx1) * (by2 - by1);
            }
            // bit-exact matched_vals[idx]: same fp ops on same inputs as phase 1
            float iou = iou_fn(s_gtb[mi*4+0], s_gtb[mi*4+1], s_gtb[mi*4+2], s_gtb[mi*4+3],
                               s_gta[mi], bx1, by1, bx2, by2, area_b);
            s_out[0][slot] = iou;
            s_out[1][slot] = (float)idx;
            s_out[2][slot] = (float)(isfg ? s_gtc[mi] : NUM_CLASSES_);
            s_out[3][slot] = (float)mi;
        }
    }
    __syncthreads();

    // ---- phase 6: coalesced write-out ----
    for (int i = tid; i < 5 * BATCH_PER; i += NTH) {
        int o = i / BATCH_PER, p = i % BATCH_PER;
        out[(size_t)o * OUT_STRIDE + (size_t)b * BATCH_PER + p] = s_out[o][p];
    }
}

extern "C" void kernel_launch(void* const* d_in, const int* in_sizes, int n_in,
                              void* d_out, int out_size, void* d_ws, size_t ws_size,
                              hipStream_t stream) {
    const float* gt_boxes   = (const float*)d_in[0];  // [64,100,4]
    const float* prop_boxes = (const float*)d_in[1];  // [64,4000,4]
    const int*   gt_classes = (const int*)  d_in[2];  // [64,100]
    const float* rand_pri   = (const float*)d_in[3];  // [64,4100]
    float* out = (float*)d_out;                       // 5 x [64,512] float32, concat

    roiheads_kernel<<<B_IMG, NTH, 0, stream>>>(gt_boxes, prop_boxes, gt_classes,
                                               rand_pri, out);
}